// Round 5
// baseline (844.077 us; speedup 1.0000x reference)
//
#include <hip/hip_runtime.h>

typedef unsigned short u16;
typedef float          f32x4 __attribute__((ext_vector_type(4)));
typedef short          s16x8 __attribute__((ext_vector_type(8)));
typedef unsigned short u16x8 __attribute__((ext_vector_type(8)));

static constexpr int BN = 8192, INF = 784, HD = 1024, LD = 128, TT = 10;
static constexpr int MTILES = 73, MCAP = MTILES * 128;
static constexpr size_t OFFMU = (size_t)BN * INF;
static constexpr size_t OFFLS = OFFMU + (size_t)BN * LD;

// workspace layout (bytes)
static constexpr size_t O_ZP   = 2048;                 // zero page (ws[0..4096) zeroed)
static constexpr size_t O_PERM = 4096;                 // MCAP ints
static constexpr size_t O_BUF  = 49152;
static constexpr size_t T_ALL  = (size_t)128 * HD * 2 * 2      // Ha + Hb
                               + (size_t)128 * 256 * 2         // ENCb
                               + (size_t)128 * LD * 2;         // Z   = 622592/tile

__device__ __forceinline__ float bf2f(u16 a){
  unsigned int u = ((unsigned int)a) << 16; float f;
  __builtin_memcpy(&f, &u, 4); return f;
}
__device__ __forceinline__ u16 f2bf(float f){
  unsigned int u; __builtin_memcpy(&u, &f, 4);
  u = u + 0x7fffu + ((u >> 16) & 1u);   // RNE
  return (u16)(u >> 16);
}
// dtype-flag-dependent output store: flag=1 -> fp32 buffer, flag=0 -> bf16 buffer
__device__ __forceinline__ void stout(void* out, size_t idx, float v, int flag){
  if(flag) ((float*)out)[idx] = v;
  else     ((u16*)out)[idx]   = f2bf(v);
}

// flag=meta[15]: 1 if float inputs are fp32, 0 if bf16.
// eps ~ N(0,1): bf16 words have exponent field <=~130; fp32 low-half (even-index)
// words carry raw mantissa bits -> ~40% of them have "exponent" field > 150.
__global__ void k_detect(const u16* __restrict__ eps, int* __restrict__ meta){
  __shared__ int cnt;
  if(threadIdx.x == 0) cnt = 0;
  __syncthreads();
  int c = 0;
  for(int i = threadIdx.x; i < 4096; i += 256){
    int e = (eps[i] >> 7) & 0xFF;
    if(e > 150) c++;
  }
  atomicAdd(&cnt, c);
  __syncthreads();
  if(threadIdx.x == 0) meta[15] = (cnt > 64) ? 1 : 0;
}

__global__ void k_count(const int* __restrict__ task, int* __restrict__ meta){
  int i = blockIdx.x * 256 + threadIdx.x;
  if(i < BN) atomicAdd(&meta[task[i]], 1);
}

// meta: [0..9]=counts, [15]=dtype flag, [16..25]=cursor, [32..41]=seg offsets, [48..120]=tile->task
__global__ void k_plan(int* __restrict__ meta){
  if(threadIdx.x == 0){
    int off = 0, tile = 0;
    for(int t = 0; t < TT; t++){
      meta[32 + t] = off;
      int nt = (meta[t] + 127) >> 7;
      for(int k = 0; k < nt; k++) meta[48 + tile + k] = t;
      tile += nt; off += nt * 128;
    }
    for(; tile < MTILES; tile++) meta[48 + tile] = 0;
  }
}

__global__ void k_scatter(const int* __restrict__ task, int* __restrict__ meta, int* __restrict__ perm){
  int i = blockIdx.x * 256 + threadIdx.x;
  if(i < BN){
    int t = task[i];
    int pos = meta[32 + t] + atomicAdd(&meta[16 + t], 1);
    perm[pos] = i;
  }
}

// ENCb(bf16, ct*128 x 256) -> mu/log_sigma scattered to d_out, z(bf16) for decoder
__global__ void k_z(const u16* __restrict__ ENCb, const void* __restrict__ eps,
                    const int* __restrict__ perm, u16* __restrict__ Z,
                    void* __restrict__ out, int t0, const int* __restrict__ meta){
  const int flag = meta[15];
  int idx = blockIdx.x * 256 + threadIdx.x;
  int pl = idx >> 7, j = idx & 127;
  int r = perm[t0 * 128 + pl];
  u16 zv = 0;
  if(r >= 0){
    u16 mb = ENCb[(size_t)pl * 256 + j];
    u16 lb = ENCb[(size_t)pl * 256 + 128 + j];
    float mu = bf2f(mb), ls = bf2f(lb);
    float e = flag ? ((const float*)eps)[(size_t)r * LD + j]
                   : bf2f(((const u16*)eps)[(size_t)r * LD + j]);
    zv = f2bf(mu + __expf(ls) * e);
    stout(out, OFFMU + (size_t)r * LD + j, mu, flag);
    stout(out, OFFLS + (size_t)r * LD + j, ls, flag);
  }
  Z[(size_t)pl * LD + j] = zv;
}

// C[128x128 tile] = act( A[m,:K] * B[:K,n] + bias[n] ); B is (K,N), transposed via LDS.
// AMODE 0: dense bf16 A (ws activations). AMODE 1: gather rows of input x via perm (dtype flag).
// EPI 0: relu->bf16 ; EPI 1: linear->bf16 ; EPI 2: sigmoid->scatter to out rows perm[m] (dtype flag)
template<int AMODE, int EPI>
__launch_bounds__(256, 2)
__global__ void k_gemm(const void* __restrict__ A, int lda,
                       const void* __restrict__ B, long long bStride, int ldbN,
                       const void* __restrict__ bias, int biasStride,
                       u16* __restrict__ C, int ldc,
                       int Kpad, int Kact, int Nact, int t0,
                       const int* __restrict__ meta, const int* __restrict__ perm,
                       const char* __restrict__ zpc, void* __restrict__ outp)
{
  __shared__ __align__(16) u16 As[128 * 64];
  __shared__ __align__(16) u16 Bs[128 * 72];   // stride 72: 16B-aligned b128 fragment reads
  const int flag = meta[15];
  const int tid  = threadIdx.x;
  const int lane = tid & 63;
  const int wave = tid >> 6;
  const int wm = (wave >> 1) << 6;
  const int wn = (wave & 1) << 6;
  const int m0l = blockIdx.x << 7;
  const int m0g = (t0 + blockIdx.x) << 7;
  const int n0 = blockIdx.y << 7;
  const int task = meta[48 + t0 + blockIdx.x];
  const int srow = tid >> 3;          // 0..31
  const int scol = (tid & 7) << 3;    // 8 elements = 16B bf16 per lane
  const int frow = lane & 15;
  const int fq   = lane >> 4;         // 0..3

  const void* abase[4];
  bool aok[4];
  #pragma unroll
  for(int i = 0; i < 4; i++){
    if(AMODE == 0){ abase[i] = (const u16*)A + (size_t)(m0l + srow + i * 32) * lda; aok[i] = true; }
    else {
      int r = perm[m0g + srow + i * 32];
      aok[i] = (r >= 0);
      if(flag) abase[i] = aok[i] ? (const void*)((const float*)A + (size_t)r * INF) : (const void*)zpc;
      else     abase[i] = aok[i] ? (const void*)((const u16*)A + (size_t)r * INF)   : (const void*)zpc;
    }
  }

  f32x4 acc[4][4];
  #pragma unroll
  for(int i = 0; i < 4; i++)
    #pragma unroll
    for(int j = 0; j < 4; j++) acc[i][j] = (f32x4)0.f;

  for(int k0 = 0; k0 < Kpad; k0 += 64){
    __syncthreads();
    // ---- A: global -> LDS, rows [0..127] x k[0..63], 16B/lane ----
    if(AMODE == 0 || !flag){
      #pragma unroll
      for(int i = 0; i < 4; i++){
        const u16* g;
        if(AMODE == 0) g = (const u16*)abase[i] + k0 + scol;
        else g = (aok[i] && (k0 + scol) < Kact) ? (const u16*)abase[i] + k0 + scol : (const u16*)zpc;
        __builtin_amdgcn_global_load_lds((const __attribute__((address_space(1))) void*)g,
          (__attribute__((address_space(3))) void*)(As + (srow + i * 32) * 64 + scol), 16, 0, 0);
      }
    } else {
      // fp32 gather path: load 8 floats, convert, store 16B to same LDS slot
      #pragma unroll
      for(int i = 0; i < 4; i++){
        const float* g = (aok[i] && (k0 + scol) < Kact) ? (const float*)abase[i] + k0 + scol
                                                        : (const float*)zpc;
        f32x4 v0 = *(const f32x4*)g;
        f32x4 v1 = *(const f32x4*)(g + 4);
        u16x8 cv;
        #pragma unroll
        for(int j = 0; j < 4; j++){ cv[j] = f2bf(v0[j]); cv[4 + j] = f2bf(v1[j]); }
        *(u16x8*)(As + (srow + i * 32) * 64 + scol) = cv;
      }
    }
    // ---- B: (K,N) -> LDS as B^T[n][k]; each lane: one k, 8 consecutive n ----
    #pragma unroll
    for(int rr = 0; rr < 4; rr++){
      int kk = lane;                        // 0..63
      int nb = (((rr << 2) + wave) << 3);   // 0..120 step 8
      int kg = k0 + kk, ng = n0 + nb;
      bool inb = (kg < Kact && ng < Nact);
      u16x8 v;
      if(!flag){
        const u16* gb = inb ? ((const u16*)B + (size_t)task * bStride + (size_t)kg * ldbN + ng)
                            : (const u16*)zpc;
        v = *(const u16x8*)gb;
      } else {
        const float* gb = inb ? ((const float*)B + (size_t)task * bStride + (size_t)kg * ldbN + ng)
                              : (const float*)zpc;
        f32x4 v0 = *(const f32x4*)gb;
        f32x4 v1 = *(const f32x4*)(gb + 4);
        #pragma unroll
        for(int j = 0; j < 4; j++){ v[j] = f2bf(v0[j]); v[4 + j] = f2bf(v1[j]); }
      }
      #pragma unroll
      for(int j = 0; j < 8; j++) Bs[(size_t)(nb + j) * 72 + kk] = v[j];
    }
    __syncthreads();
    // ---- MFMA: 2 k-halves of 32 ----
    #pragma unroll
    for(int s = 0; s < 2; s++){
      s16x8 af[4], bfr[4];
      #pragma unroll
      for(int i = 0; i < 4; i++)
        af[i]  = *(const s16x8*)(As + (wm + i * 16 + frow) * 64 + s * 32 + fq * 8);
      #pragma unroll
      for(int j = 0; j < 4; j++)
        bfr[j] = *(const s16x8*)(Bs + (size_t)(wn + j * 16 + frow) * 72 + s * 32 + fq * 8);
      #pragma unroll
      for(int i = 0; i < 4; i++)
        #pragma unroll
        for(int j = 0; j < 4; j++)
          acc[i][j] = __builtin_amdgcn_mfma_f32_16x16x32_bf16(af[i], bfr[j], acc[i][j], 0, 0, 0);
    }
  }

  const int crow = fq << 2;   // C/D: col=lane&15, row=(lane>>4)*4+reg [m89]
  const int ccol = frow;
  auto bload = [&](int idx) -> float {
    return flag ? ((const float*)bias)[idx] : bf2f(((const u16*)bias)[idx]);
  };

  if(EPI < 2){
    #pragma unroll
    for(int j = 0; j < 4; j++){
      int n = n0 + wn + j * 16 + ccol;
      float bv = bload(task * biasStride + n);
      #pragma unroll
      for(int i = 0; i < 4; i++)
        #pragma unroll
        for(int r = 0; r < 4; r++){
          int m = m0l + wm + i * 16 + crow + r;
          float v = acc[i][j][r] + bv;
          if(EPI == 0 && v < 0.f) v = 0.f;
          C[(size_t)m * ldc + n] = f2bf(v);
        }
    }
  } else {
    int rp[4][4];
    #pragma unroll
    for(int i = 0; i < 4; i++)
      #pragma unroll
      for(int r = 0; r < 4; r++)
        rp[i][r] = perm[m0g + wm + i * 16 + crow + r];
    #pragma unroll
    for(int j = 0; j < 4; j++){
      int n = n0 + wn + j * 16 + ccol;
      if(n < Nact){
        float bv = bload(task * biasStride + n);
        #pragma unroll
        for(int i = 0; i < 4; i++)
          #pragma unroll
          for(int r = 0; r < 4; r++){
            int rr = rp[i][r];
            if(rr >= 0){
              float v = acc[i][j][r] + bv;
              stout(outp, (size_t)rr * INF + n, 1.f / (1.f + __expf(-v)), flag);
            }
          }
      }
    }
  }
}

extern "C" void kernel_launch(void* const* d_in, const int* in_sizes, int n_in,
                              void* d_out, int out_size, void* d_ws, size_t ws_size,
                              hipStream_t stream) {
  const void* x    = d_in[0];
  const int*  task = (const int*)d_in[1];
  const void* eps  = d_in[2];
  const void* W1  = d_in[3];  const void* b1  = d_in[4];
  const void* W2  = d_in[5];  const void* b2  = d_in[6];
  const void* W3  = d_in[7];  const void* b3  = d_in[8];
  const void* W4  = d_in[9];  const void* b4  = d_in[10];
  const void* Ws1 = d_in[11]; const void* bs1 = d_in[12];
  const void* Ws2 = d_in[13]; const void* bs2 = d_in[14];
  const void* Wh1 = d_in[15]; const void* bh1 = d_in[16];
  const void* Wh2 = d_in[17]; const void* bh2 = d_in[18];
  void* out = d_out;
  char* ws  = (char*)d_ws;

  int* meta = (int*)ws;
  const char* zp = ws + O_ZP;
  int* perm = (int*)(ws + O_PERM);

  size_t avail = ws_size > O_BUF ? ws_size - O_BUF : 0;
  int CH = (int)(avail / T_ALL);
  if(CH < 1) CH = 1;
  if(CH > MTILES) CH = MTILES;

  u16* Ha   = (u16*)(ws + O_BUF);
  u16* Hb   = Ha + (size_t)CH * 128 * HD;
  u16* ENCb = Hb + (size_t)CH * 128 * HD;
  u16* Z    = ENCb + (size_t)CH * 128 * 256;

  (void)hipMemsetAsync(ws, 0, 4096, stream);                  // meta + zero page
  (void)hipMemsetAsync(perm, 0xFF, (size_t)MCAP * 4, stream); // pad rows = -1
  k_detect <<<1, 256, 0, stream>>>((const u16*)eps, meta);
  k_count  <<<32, 256, 0, stream>>>(task, meta);
  k_plan   <<<1, 64, 0, stream>>>(meta);
  k_scatter<<<32, 256, 0, stream>>>(task, meta, perm);

  for(int t0 = 0; t0 < MTILES; t0 += CH){
    int ct = (MTILES - t0 < CH) ? (MTILES - t0) : CH;
    // enc1: gather x (K=784 pad 832) * W1 -> Ha, relu
    k_gemm<1,0><<<dim3(ct,8), 256, 0, stream>>>(x, INF, W1, (long long)INF*HD, HD,
                                                b1, HD, Ha, HD, 832, INF, HD, t0, meta, perm, zp, out);
    // enc2
    k_gemm<0,0><<<dim3(ct,8), 256, 0, stream>>>(Ha, HD, W2, (long long)HD*HD, HD,
                                                b2, HD, Hb, HD, HD, HD, HD, t0, meta, perm, zp, out);
    // enc3
    k_gemm<0,0><<<dim3(ct,8), 256, 0, stream>>>(Hb, HD, W3, (long long)HD*HD, HD,
                                                b3, HD, Ha, HD, HD, HD, HD, t0, meta, perm, zp, out);
    // enc4 -> ENCb (bf16, 256 wide)
    k_gemm<0,1><<<dim3(ct,2), 256, 0, stream>>>(Ha, HD, W4, (long long)HD*256, 256,
                                                b4, 256, ENCb, 256, HD, HD, 256, t0, meta, perm, zp, out);
    // mu / log_sigma to d_out + z
    k_z<<<ct*64, 256, 0, stream>>>(ENCb, eps, perm, Z, out, t0, meta);
    // dec s1 (shared weights): Z(K=128) * Ws1 -> Ha, relu
    k_gemm<0,0><<<dim3(ct,8), 256, 0, stream>>>(Z, LD, Ws1, 0LL, HD,
                                                bs1, 0, Ha, HD, LD, LD, HD, t0, meta, perm, zp, out);
    // dec s2 (shared)
    k_gemm<0,0><<<dim3(ct,8), 256, 0, stream>>>(Ha, HD, Ws2, 0LL, HD,
                                                bs2, 0, Hb, HD, HD, HD, HD, t0, meta, perm, zp, out);
    // dec h1 (per-task)
    k_gemm<0,0><<<dim3(ct,8), 256, 0, stream>>>(Hb, HD, Wh1, (long long)HD*HD, HD,
                                                bh1, HD, Ha, HD, HD, HD, HD, t0, meta, perm, zp, out);
    // dec h2 (per-task): sigmoid + scatter to d_out x_prime (N=784)
    k_gemm<0,2><<<dim3(ct,7), 256, 0, stream>>>(Ha, HD, Wh2, (long long)HD*INF, INF,
                                                bh2, INF, (u16*)out, INF, HD, HD, INF, t0, meta, perm, zp, out);
  }
}

// Round 6
// 688.641 us; speedup vs baseline: 1.2257x; 1.2257x over previous
//
#include <hip/hip_runtime.h>

typedef unsigned short u16;
typedef float          f32x4 __attribute__((ext_vector_type(4)));
typedef short          s16x8 __attribute__((ext_vector_type(8)));
typedef unsigned short u16x4 __attribute__((ext_vector_type(4)));
typedef unsigned short u16x8 __attribute__((ext_vector_type(8)));

static constexpr int BN = 8192, INF = 784, HD = 1024, LD = 128, TT = 10;
static constexpr int MTILES = 73, MCAP = MTILES * 128;
static constexpr size_t OFFMU = (size_t)BN * INF;
static constexpr size_t OFFLS = OFFMU + (size_t)BN * LD;

// workspace layout (bytes)
static constexpr size_t O_ZP   = 2048;                 // zero page (ws[0..4096) zeroed)
static constexpr size_t O_PERM = 4096;                 // MCAP ints
static constexpr size_t O_WT   = 49152;                // transposed-weight slab (reused per layer)
static constexpr size_t SZ_WT  = (size_t)TT * HD * HD * 2;   // 20.97 MB (max layer)
static constexpr size_t O_BUF  = O_WT + SZ_WT;
static constexpr size_t T_ALL  = (size_t)128 * HD * 2 * 2      // Ha + Hb
                               + (size_t)128 * 256 * 2         // ENCb
                               + (size_t)128 * LD * 2;         // Z   = 622592/tile

__device__ __forceinline__ float bf2f(u16 a){
  unsigned int u = ((unsigned int)a) << 16; float f;
  __builtin_memcpy(&f, &u, 4); return f;
}
__device__ __forceinline__ u16 f2bf(float f){
  unsigned int u; __builtin_memcpy(&u, &f, 4);
  u = u + 0x7fffu + ((u >> 16) & 1u);   // RNE
  return (u16)(u >> 16);
}
__device__ __forceinline__ void stout(void* out, size_t idx, float v, int flag){
  if(flag) ((float*)out)[idx] = v;
  else     ((u16*)out)[idx]   = f2bf(v);
}

// flag=meta[15]: 1 if float inputs are fp32, 0 if bf16 (verified r5: fp32).
__global__ void k_detect(const u16* __restrict__ eps, int* __restrict__ meta){
  __shared__ int cnt;
  if(threadIdx.x == 0) cnt = 0;
  __syncthreads();
  int c = 0;
  for(int i = threadIdx.x; i < 4096; i += 256){
    int e = (eps[i] >> 7) & 0xFF;
    if(e > 150) c++;
  }
  atomicAdd(&cnt, c);
  __syncthreads();
  if(threadIdx.x == 0) meta[15] = (cnt > 64) ? 1 : 0;
}

__global__ void k_count(const int* __restrict__ task, int* __restrict__ meta){
  int i = blockIdx.x * 256 + threadIdx.x;
  if(i < BN) atomicAdd(&meta[task[i]], 1);
}

// meta: [0..9]=counts, [15]=dtype flag, [16..25]=cursor, [32..41]=seg offsets, [48..120]=tile->task
__global__ void k_plan(int* __restrict__ meta){
  if(threadIdx.x == 0){
    int off = 0, tile = 0;
    for(int t = 0; t < TT; t++){
      meta[32 + t] = off;
      int nt = (meta[t] + 127) >> 7;
      for(int k = 0; k < nt; k++) meta[48 + tile + k] = t;
      tile += nt; off += nt * 128;
    }
    for(; tile < MTILES; tile++) meta[48 + tile] = 0;
  }
}

__global__ void k_scatter(const int* __restrict__ task, int* __restrict__ meta, int* __restrict__ perm){
  int i = blockIdx.x * 256 + threadIdx.x;
  if(i < BN){
    int t = task[i];
    int pos = meta[32 + t] + atomicAdd(&meta[16 + t], 1);
    perm[pos] = i;
  }
}

// weight transpose+convert: S (T,KI,NI) fp32/bf16 -> D (T,NO,KO) bf16, zero-padded
__global__ void k_wt(const void* __restrict__ S0, int KI, int NI,
                     u16* __restrict__ D0, int KO, int NO,
                     const int* __restrict__ meta){
  __shared__ u16 tile[32][36];
  const int flag = meta[15];
  const int t = blockIdx.z;
  u16* D = D0 + (size_t)t * NO * KO;
  const int k0 = blockIdx.x << 5, n0 = blockIdx.y << 5;
  const int r = threadIdx.x >> 3, c4 = (threadIdx.x & 7) << 2;
  const int k = k0 + r, n = n0 + c4;
  u16 v[4] = {0, 0, 0, 0};
  if(k < KI){
    if(flag){
      const float* S = (const float*)S0 + ((size_t)t * KI + k) * NI;
      if(n + 3 < NI){ f32x4 f = *(const f32x4*)(S + n);
        #pragma unroll
        for(int j = 0; j < 4; j++) v[j] = f2bf(f[j]); }
      else { for(int j = 0; j < 4; j++) if(n + j < NI) v[j] = f2bf(S[n + j]); }
    } else {
      const u16* S = (const u16*)S0 + ((size_t)t * KI + k) * NI;
      if(n + 3 < NI){ u16x4 f = *(const u16x4*)(S + n);
        #pragma unroll
        for(int j = 0; j < 4; j++) v[j] = f[j]; }
      else { for(int j = 0; j < 4; j++) if(n + j < NI) v[j] = S[n + j]; }
    }
  }
  #pragma unroll
  for(int j = 0; j < 4; j++) tile[r][c4 + j] = v[j];
  __syncthreads();
  u16x4 o;
  #pragma unroll
  for(int j = 0; j < 4; j++) o[j] = tile[c4 + j][r];
  *(u16x4*)(D + (size_t)(n0 + r) * KO + k0 + c4) = o;
}

// ENCb(bf16) -> mu/log_sigma scattered to d_out, z(bf16) for decoder
__global__ void k_z(const u16* __restrict__ ENCb, const void* __restrict__ eps,
                    const int* __restrict__ perm, u16* __restrict__ Z,
                    void* __restrict__ out, int t0, const int* __restrict__ meta){
  const int flag = meta[15];
  int idx = blockIdx.x * 256 + threadIdx.x;
  int pl = idx >> 7, j = idx & 127;
  int r = perm[t0 * 128 + pl];
  u16 zv = 0;
  if(r >= 0){
    u16 mb = ENCb[(size_t)pl * 256 + j];
    u16 lb = ENCb[(size_t)pl * 256 + 128 + j];
    float mu = bf2f(mb), ls = bf2f(lb);
    float e = flag ? ((const float*)eps)[(size_t)r * LD + j]
                   : bf2f(((const u16*)eps)[(size_t)r * LD + j]);
    zv = f2bf(mu + __expf(ls) * e);
    stout(out, OFFMU + (size_t)r * LD + j, mu, flag);
    stout(out, OFFLS + (size_t)r * LD + j, ls, flag);
  }
  Z[(size_t)pl * LD + j] = zv;
}

// C[128x128 tile] = act( A[m,:K] * Bt[n,:K]^T + bias[n] ); Bt is bf16 (task,N,Kpad) zero-padded.
// AMODE 0: dense bf16 A. AMODE 1: gather rows of input x via perm (dtype flag).
// EPI 0: relu->bf16 ; EPI 1: linear->bf16 ; EPI 2: sigmoid->scatter to out rows perm[m]
template<int AMODE, int EPI>
__launch_bounds__(256, 2)
__global__ void k_gemm(const void* __restrict__ A, int lda,
                       const u16* __restrict__ Bt, long long bStride,
                       const void* __restrict__ bias, int biasStride,
                       u16* __restrict__ C, int ldc,
                       int Kpad, int Kact, int Nact, int t0,
                       const int* __restrict__ meta, const int* __restrict__ perm,
                       const char* __restrict__ zpc, void* __restrict__ outp)
{
  __shared__ __align__(16) u16 As[128 * 64];
  __shared__ __align__(16) u16 Bs[128 * 64];
  const int flag = meta[15];
  const int tid  = threadIdx.x;
  const int lane = tid & 63;
  const int wave = tid >> 6;
  const int wm = (wave >> 1) << 6;
  const int wn = (wave & 1) << 6;
  const int m0l = blockIdx.x << 7;
  const int m0g = (t0 + blockIdx.x) << 7;
  const int n0 = blockIdx.y << 7;
  const int task = meta[48 + t0 + blockIdx.x];
  const int srow = tid >> 3;          // 0..31
  const int scol = (tid & 7) << 3;    // 8 elements = 16B bf16 per lane
  const int frow = lane & 15;
  const int fq   = lane >> 4;         // 0..3

  const void* abase[4];
  bool aok[4];
  #pragma unroll
  for(int i = 0; i < 4; i++){
    if(AMODE == 0){ abase[i] = (const u16*)A + (size_t)(m0l + srow + i * 32) * lda; aok[i] = true; }
    else {
      int r = perm[m0g + srow + i * 32];
      aok[i] = (r >= 0);
      if(flag) abase[i] = aok[i] ? (const void*)((const float*)A + (size_t)r * INF) : (const void*)zpc;
      else     abase[i] = aok[i] ? (const void*)((const u16*)A + (size_t)r * INF)   : (const void*)zpc;
    }
  }
  const u16* Bp = Bt + (size_t)task * bStride + (size_t)n0 * Kpad;

  f32x4 acc[4][4];
  #pragma unroll
  for(int i = 0; i < 4; i++)
    #pragma unroll
    for(int j = 0; j < 4; j++) acc[i][j] = (f32x4)0.f;

  for(int k0 = 0; k0 < Kpad; k0 += 64){
    __syncthreads();
    // ---- A: global -> LDS, rows [0..127] x k[0..63], 16B/lane ----
    if(AMODE == 0 || !flag){
      #pragma unroll
      for(int i = 0; i < 4; i++){
        const u16* g;
        if(AMODE == 0) g = (const u16*)abase[i] + k0 + scol;
        else g = (aok[i] && (k0 + scol) < Kact) ? (const u16*)abase[i] + k0 + scol : (const u16*)zpc;
        __builtin_amdgcn_global_load_lds((const __attribute__((address_space(1))) void*)g,
          (__attribute__((address_space(3))) void*)(As + (srow + i * 32) * 64 + scol), 16, 0, 0);
      }
    } else {
      // fp32 gather path (enc1): load 8 floats, convert, store 16B
      #pragma unroll
      for(int i = 0; i < 4; i++){
        const float* g = (aok[i] && (k0 + scol) < Kact) ? (const float*)abase[i] + k0 + scol
                                                        : (const float*)zpc;
        f32x4 v0 = *(const f32x4*)g;
        f32x4 v1 = *(const f32x4*)(g + 4);
        u16x8 cv;
        #pragma unroll
        for(int j = 0; j < 4; j++){ cv[j] = f2bf(v0[j]); cv[4 + j] = f2bf(v1[j]); }
        *(u16x8*)(As + (srow + i * 32) * 64 + scol) = cv;
      }
    }
    // ---- B: pre-transposed bf16 (N,Kpad) -> LDS, same coalesced path ----
    #pragma unroll
    for(int i = 0; i < 4; i++){
      const u16* g = Bp + (size_t)(srow + i * 32) * Kpad + k0 + scol;
      __builtin_amdgcn_global_load_lds((const __attribute__((address_space(1))) void*)g,
        (__attribute__((address_space(3))) void*)(Bs + (srow + i * 32) * 64 + scol), 16, 0, 0);
    }
    __syncthreads();
    // ---- MFMA: 2 k-halves of 32 ----
    #pragma unroll
    for(int s = 0; s < 2; s++){
      s16x8 af[4], bfr[4];
      #pragma unroll
      for(int i = 0; i < 4; i++)
        af[i]  = *(const s16x8*)(As + (wm + i * 16 + frow) * 64 + s * 32 + fq * 8);
      #pragma unroll
      for(int j = 0; j < 4; j++)
        bfr[j] = *(const s16x8*)(Bs + (wn + j * 16 + frow) * 64 + s * 32 + fq * 8);
      #pragma unroll
      for(int i = 0; i < 4; i++)
        #pragma unroll
        for(int j = 0; j < 4; j++)
          acc[i][j] = __builtin_amdgcn_mfma_f32_16x16x32_bf16(af[i], bfr[j], acc[i][j], 0, 0, 0);
    }
  }

  const int crow = fq << 2;   // C/D: col=lane&15, row=(lane>>4)*4+reg [m89]
  const int ccol = frow;
  auto bload = [&](int idx) -> float {
    return flag ? ((const float*)bias)[idx] : bf2f(((const u16*)bias)[idx]);
  };

  if(EPI < 2){
    #pragma unroll
    for(int j = 0; j < 4; j++){
      int n = n0 + wn + j * 16 + ccol;
      float bv = bload(task * biasStride + n);
      #pragma unroll
      for(int i = 0; i < 4; i++)
        #pragma unroll
        for(int r = 0; r < 4; r++){
          int m = m0l + wm + i * 16 + crow + r;
          float v = acc[i][j][r] + bv;
          if(EPI == 0 && v < 0.f) v = 0.f;
          C[(size_t)m * ldc + n] = f2bf(v);
        }
    }
  } else {
    int rp[4][4];
    #pragma unroll
    for(int i = 0; i < 4; i++)
      #pragma unroll
      for(int r = 0; r < 4; r++)
        rp[i][r] = perm[m0g + wm + i * 16 + crow + r];
    #pragma unroll
    for(int j = 0; j < 4; j++){
      int n = n0 + wn + j * 16 + ccol;
      if(n < Nact){
        float bv = bload(task * biasStride + n);
        #pragma unroll
        for(int i = 0; i < 4; i++)
          #pragma unroll
          for(int r = 0; r < 4; r++){
            int rr = rp[i][r];
            if(rr >= 0){
              float v = acc[i][j][r] + bv;
              stout(outp, (size_t)rr * INF + n, 1.f / (1.f + __expf(-v)), flag);
            }
          }
      }
    }
  }
}

extern "C" void kernel_launch(void* const* d_in, const int* in_sizes, int n_in,
                              void* d_out, int out_size, void* d_ws, size_t ws_size,
                              hipStream_t stream) {
  const void* x    = d_in[0];
  const int*  task = (const int*)d_in[1];
  const void* eps  = d_in[2];
  const void* W1  = d_in[3];  const void* b1  = d_in[4];
  const void* W2  = d_in[5];  const void* b2  = d_in[6];
  const void* W3  = d_in[7];  const void* b3  = d_in[8];
  const void* W4  = d_in[9];  const void* b4  = d_in[10];
  const void* Ws1 = d_in[11]; const void* bs1 = d_in[12];
  const void* Ws2 = d_in[13]; const void* bs2 = d_in[14];
  const void* Wh1 = d_in[15]; const void* bh1 = d_in[16];
  const void* Wh2 = d_in[17]; const void* bh2 = d_in[18];
  void* out = d_out;
  char* ws  = (char*)d_ws;

  int* meta = (int*)ws;
  const char* zp = ws + O_ZP;
  int* perm = (int*)(ws + O_PERM);
  u16* Wt   = (u16*)(ws + O_WT);

  size_t avail = ws_size > O_BUF ? ws_size - O_BUF : 0;
  int CH = (int)(avail / T_ALL);
  if(CH < 1) CH = 1;
  if(CH > MTILES) CH = MTILES;

  u16* Ha   = (u16*)(ws + O_BUF);
  u16* Hb   = Ha + (size_t)CH * 128 * HD;
  u16* ENCb = Hb + (size_t)CH * 128 * HD;
  u16* Z    = ENCb + (size_t)CH * 128 * 256;

  (void)hipMemsetAsync(ws, 0, 4096, stream);                  // meta + zero page
  (void)hipMemsetAsync(perm, 0xFF, (size_t)MCAP * 4, stream); // pad rows = -1
  k_detect <<<1, 256, 0, stream>>>((const u16*)eps, meta);
  k_count  <<<32, 256, 0, stream>>>(task, meta);
  k_plan   <<<1, 64, 0, stream>>>(meta);
  k_scatter<<<32, 256, 0, stream>>>(task, meta, perm);

  for(int t0 = 0; t0 < MTILES; t0 += CH){
    int ct = (MTILES - t0 < CH) ? (MTILES - t0) : CH;
    // enc1: gather x (K=784 pad 832) * W1t -> Ha, relu
    k_wt<<<dim3(26, 32, TT), 256, 0, stream>>>(W1, INF, HD, Wt, 832, HD, meta);
    k_gemm<1,0><<<dim3(ct,8), 256, 0, stream>>>(x, INF, Wt, (long long)HD*832,
                                                b1, HD, Ha, HD, 832, INF, HD, t0, meta, perm, zp, out);
    // enc2
    k_wt<<<dim3(32, 32, TT), 256, 0, stream>>>(W2, HD, HD, Wt, HD, HD, meta);
    k_gemm<0,0><<<dim3(ct,8), 256, 0, stream>>>(Ha, HD, Wt, (long long)HD*HD,
                                                b2, HD, Hb, HD, HD, HD, HD, t0, meta, perm, zp, out);
    // enc3
    k_wt<<<dim3(32, 32, TT), 256, 0, stream>>>(W3, HD, HD, Wt, HD, HD, meta);
    k_gemm<0,0><<<dim3(ct,8), 256, 0, stream>>>(Hb, HD, Wt, (long long)HD*HD,
                                                b3, HD, Ha, HD, HD, HD, HD, t0, meta, perm, zp, out);
    // enc4 -> ENCb (bf16, 256 wide)
    k_wt<<<dim3(32, 8, TT), 256, 0, stream>>>(W4, HD, 256, Wt, HD, 256, meta);
    k_gemm<0,1><<<dim3(ct,2), 256, 0, stream>>>(Ha, HD, Wt, (long long)256*HD,
                                                b4, 256, ENCb, 256, HD, HD, 256, t0, meta, perm, zp, out);
    // mu / log_sigma to d_out + z
    k_z<<<ct*64, 256, 0, stream>>>(ENCb, eps, perm, Z, out, t0, meta);
    // dec s1 (shared): Z(K=128) * Ws1t -> Ha, relu
    k_wt<<<dim3(4, 32, 1), 256, 0, stream>>>(Ws1, LD, HD, Wt, LD, HD, meta);
    k_gemm<0,0><<<dim3(ct,8), 256, 0, stream>>>(Z, LD, Wt, 0LL,
                                                bs1, 0, Ha, HD, LD, LD, HD, t0, meta, perm, zp, out);
    // dec s2 (shared)
    k_wt<<<dim3(32, 32, 1), 256, 0, stream>>>(Ws2, HD, HD, Wt, HD, HD, meta);
    k_gemm<0,0><<<dim3(ct,8), 256, 0, stream>>>(Ha, HD, Wt, 0LL,
                                                bs2, 0, Hb, HD, HD, HD, HD, t0, meta, perm, zp, out);
    // dec h1 (per-task)
    k_wt<<<dim3(32, 32, TT), 256, 0, stream>>>(Wh1, HD, HD, Wt, HD, HD, meta);
    k_gemm<0,0><<<dim3(ct,8), 256, 0, stream>>>(Hb, HD, Wt, (long long)HD*HD,
                                                bh1, HD, Ha, HD, HD, HD, HD, t0, meta, perm, zp, out);
    // dec h2 (per-task): sigmoid + scatter to d_out (N=784 pad 896)
    k_wt<<<dim3(32, 28, TT), 256, 0, stream>>>(Wh2, HD, INF, Wt, HD, 896, meta);
    k_gemm<0,2><<<dim3(ct,7), 256, 0, stream>>>(Ha, HD, Wt, (long long)896*HD,
                                                bh2, INF, (u16*)out, INF, HD, HD, INF, t0, meta, perm, zp, out);
  }
}

// Round 7
// 650.068 us; speedup vs baseline: 1.2984x; 1.0593x over previous
//
#include <hip/hip_runtime.h>

typedef unsigned short u16;
typedef float          f32x4 __attribute__((ext_vector_type(4)));
typedef short          s16x8 __attribute__((ext_vector_type(8)));
typedef unsigned short u16x4 __attribute__((ext_vector_type(4)));
typedef unsigned short u16x8 __attribute__((ext_vector_type(8)));

static constexpr int BN = 8192, INF = 784, HD = 1024, LD = 128, TT = 10;
static constexpr int MTILES = 73, MCAP = MTILES * 128;
static constexpr size_t OFFMU = (size_t)BN * INF;
static constexpr size_t OFFLS = OFFMU + (size_t)BN * LD;

// workspace layout (bytes)
static constexpr size_t O_ZP   = 2048;                 // zero page (ws[0..4096) zeroed)
static constexpr size_t O_PERM = 4096;                 // MCAP ints
static constexpr size_t O_WT   = 49152;                // transposed-weight slab (reused per layer)
static constexpr size_t SZ_WT  = (size_t)TT * HD * HD * 2;   // 20.97 MB (max layer)
static constexpr size_t O_BUF  = O_WT + SZ_WT;
static constexpr size_t T_ALL  = (size_t)128 * HD * 2 * 2      // Ha + Hb
                               + (size_t)128 * 256 * 2         // ENCb
                               + (size_t)128 * LD * 2;         // Z   = 622592/tile

__device__ __forceinline__ float bf2f(u16 a){
  unsigned int u = ((unsigned int)a) << 16; float f;
  __builtin_memcpy(&f, &u, 4); return f;
}
__device__ __forceinline__ u16 f2bf(float f){
  unsigned int u; __builtin_memcpy(&u, &f, 4);
  u = u + 0x7fffu + ((u >> 16) & 1u);   // RNE
  return (u16)(u >> 16);
}
__device__ __forceinline__ void stout(void* out, size_t idx, float v, int flag){
  if(flag) ((float*)out)[idx] = v;
  else     ((u16*)out)[idx]   = f2bf(v);
}

// flag=meta[15]: 1 if float inputs are fp32, 0 if bf16 (verified r5: fp32).
__global__ void k_detect(const u16* __restrict__ eps, int* __restrict__ meta){
  __shared__ int cnt;
  if(threadIdx.x == 0) cnt = 0;
  __syncthreads();
  int c = 0;
  for(int i = threadIdx.x; i < 4096; i += 256){
    int e = (eps[i] >> 7) & 0xFF;
    if(e > 150) c++;
  }
  atomicAdd(&cnt, c);
  __syncthreads();
  if(threadIdx.x == 0) meta[15] = (cnt > 64) ? 1 : 0;
}

__global__ void k_count(const int* __restrict__ task, int* __restrict__ meta){
  int i = blockIdx.x * 256 + threadIdx.x;
  if(i < BN) atomicAdd(&meta[task[i]], 1);
}

// meta: [0..9]=counts, [15]=dtype flag, [16..25]=cursor, [32..41]=seg offsets, [48..120]=tile->task
__global__ void k_plan(int* __restrict__ meta){
  if(threadIdx.x == 0){
    int off = 0, tile = 0;
    for(int t = 0; t < TT; t++){
      meta[32 + t] = off;
      int nt = (meta[t] + 127) >> 7;
      for(int k = 0; k < nt; k++) meta[48 + tile + k] = t;
      tile += nt; off += nt * 128;
    }
    for(; tile < MTILES; tile++) meta[48 + tile] = 0;
  }
}

__global__ void k_scatter(const int* __restrict__ task, int* __restrict__ meta, int* __restrict__ perm){
  int i = blockIdx.x * 256 + threadIdx.x;
  if(i < BN){
    int t = task[i];
    int pos = meta[32 + t] + atomicAdd(&meta[16 + t], 1);
    perm[pos] = i;
  }
}

// weight transpose+convert: S (T,KI,NI) fp32/bf16 -> D (T,NO,KO) bf16, zero-padded
__global__ void k_wt(const void* __restrict__ S0, int KI, int NI,
                     u16* __restrict__ D0, int KO, int NO,
                     const int* __restrict__ meta){
  __shared__ u16 tile[32][36];
  const int flag = meta[15];
  const int t = blockIdx.z;
  u16* D = D0 + (size_t)t * NO * KO;
  const int k0 = blockIdx.x << 5, n0 = blockIdx.y << 5;
  const int r = threadIdx.x >> 3, c4 = (threadIdx.x & 7) << 2;
  const int k = k0 + r, n = n0 + c4;
  u16 v[4] = {0, 0, 0, 0};
  if(k < KI){
    if(flag){
      const float* S = (const float*)S0 + ((size_t)t * KI + k) * NI;
      if(n + 3 < NI){ f32x4 f = *(const f32x4*)(S + n);
        #pragma unroll
        for(int j = 0; j < 4; j++) v[j] = f2bf(f[j]); }
      else { for(int j = 0; j < 4; j++) if(n + j < NI) v[j] = f2bf(S[n + j]); }
    } else {
      const u16* S = (const u16*)S0 + ((size_t)t * KI + k) * NI;
      if(n + 3 < NI){ u16x4 f = *(const u16x4*)(S + n);
        #pragma unroll
        for(int j = 0; j < 4; j++) v[j] = f[j]; }
      else { for(int j = 0; j < 4; j++) if(n + j < NI) v[j] = S[n + j]; }
    }
  }
  #pragma unroll
  for(int j = 0; j < 4; j++) tile[r][c4 + j] = v[j];
  __syncthreads();
  u16x4 o;
  #pragma unroll
  for(int j = 0; j < 4; j++) o[j] = tile[c4 + j][r];
  *(u16x4*)(D + (size_t)(n0 + r) * KO + k0 + c4) = o;
}

// ENCb(bf16) -> mu/log_sigma scattered to d_out, z(bf16) for decoder
__global__ void k_z(const u16* __restrict__ ENCb, const void* __restrict__ eps,
                    const int* __restrict__ perm, u16* __restrict__ Z,
                    void* __restrict__ out, int t0, const int* __restrict__ meta){
  const int flag = meta[15];
  int idx = blockIdx.x * 256 + threadIdx.x;
  int pl = idx >> 7, j = idx & 127;
  int r = perm[t0 * 128 + pl];
  u16 zv = 0;
  if(r >= 0){
    u16 mb = ENCb[(size_t)pl * 256 + j];
    u16 lb = ENCb[(size_t)pl * 256 + 128 + j];
    float mu = bf2f(mb), ls = bf2f(lb);
    float e = flag ? ((const float*)eps)[(size_t)r * LD + j]
                   : bf2f(((const u16*)eps)[(size_t)r * LD + j]);
    zv = f2bf(mu + __expf(ls) * e);
    stout(out, OFFMU + (size_t)r * LD + j, mu, flag);
    stout(out, OFFLS + (size_t)r * LD + j, ls, flag);
  }
  Z[(size_t)pl * LD + j] = zv;
}

// C[128x128 tile] = act( A[m,:K] * Bt[n,:K]^T + bias[n] ); Bt is bf16 (task,N,Kpad) zero-padded.
// 1-D grid, nb = blockIdx.x % NB: with round-robin block->XCD placement each XCD pins
// (nearly) one n-block, so its B working set (10 tasks x 256KB) fits the 4MB per-XCD L2.
// AMODE 0: dense bf16 A. AMODE 1: gather rows of input x via perm (dtype flag).
// EPI 0: relu->bf16 ; EPI 1: linear->bf16 ; EPI 2: sigmoid->scatter to out rows perm[m]
template<int AMODE, int EPI>
__launch_bounds__(256, 4)
__global__ void k_gemm(const void* __restrict__ A, int lda,
                       const u16* __restrict__ Bt, long long bStride,
                       const void* __restrict__ bias, int biasStride,
                       u16* __restrict__ C, int ldc,
                       int Kpad, int Kact, int Nact, int t0, int NB,
                       const int* __restrict__ meta, const int* __restrict__ perm,
                       const char* __restrict__ zpc, void* __restrict__ outp)
{
  __shared__ __align__(16) u16 As[128 * 64];
  __shared__ __align__(16) u16 Bs[128 * 64];
  const int flag = meta[15];
  const int tid  = threadIdx.x;
  const int lane = tid & 63;
  const int wave = tid >> 6;
  const int wm = (wave >> 1) << 6;
  const int wn = (wave & 1) << 6;
  const int nb = blockIdx.x % NB;
  const int mt = blockIdx.x / NB;
  const int m0l = mt << 7;
  const int m0g = (t0 + mt) << 7;
  const int n0 = nb << 7;
  const int task = meta[48 + t0 + mt];
  const int srow = tid >> 3;          // 0..31
  const int scol = (tid & 7) << 3;    // 8 elements = 16B bf16 per lane
  const int frow = lane & 15;
  const int fq   = lane >> 4;         // 0..3

  const void* abase[4];
  bool aok[4];
  #pragma unroll
  for(int i = 0; i < 4; i++){
    if(AMODE == 0){ abase[i] = (const u16*)A + (size_t)(m0l + srow + i * 32) * lda; aok[i] = true; }
    else {
      int r = perm[m0g + srow + i * 32];
      aok[i] = (r >= 0);
      if(flag) abase[i] = aok[i] ? (const void*)((const float*)A + (size_t)r * INF) : (const void*)zpc;
      else     abase[i] = aok[i] ? (const void*)((const u16*)A + (size_t)r * INF)   : (const void*)zpc;
    }
  }
  const u16* Bp = Bt + (size_t)task * bStride + (size_t)n0 * Kpad;

  f32x4 acc[4][4];
  #pragma unroll
  for(int i = 0; i < 4; i++)
    #pragma unroll
    for(int j = 0; j < 4; j++) acc[i][j] = (f32x4)0.f;

  for(int k0 = 0; k0 < Kpad; k0 += 64){
    __syncthreads();
    // ---- A: global -> LDS, rows [0..127] x k[0..63], 16B/lane ----
    if(AMODE == 0 || !flag){
      #pragma unroll
      for(int i = 0; i < 4; i++){
        const u16* g;
        if(AMODE == 0) g = (const u16*)abase[i] + k0 + scol;
        else g = (aok[i] && (k0 + scol) < Kact) ? (const u16*)abase[i] + k0 + scol : (const u16*)zpc;
        __builtin_amdgcn_global_load_lds((const __attribute__((address_space(1))) void*)g,
          (__attribute__((address_space(3))) void*)(As + (srow + i * 32) * 64 + scol), 16, 0, 0);
      }
    } else {
      // fp32 gather path (enc1): load 8 floats, convert, store 16B
      #pragma unroll
      for(int i = 0; i < 4; i++){
        const float* g = (aok[i] && (k0 + scol) < Kact) ? (const float*)abase[i] + k0 + scol
                                                        : (const float*)zpc;
        f32x4 v0 = *(const f32x4*)g;
        f32x4 v1 = *(const f32x4*)(g + 4);
        u16x8 cv;
        #pragma unroll
        for(int j = 0; j < 4; j++){ cv[j] = f2bf(v0[j]); cv[4 + j] = f2bf(v1[j]); }
        *(u16x8*)(As + (srow + i * 32) * 64 + scol) = cv;
      }
    }
    // ---- B: pre-transposed bf16 (N,Kpad) -> LDS, same coalesced path ----
    #pragma unroll
    for(int i = 0; i < 4; i++){
      const u16* g = Bp + (size_t)(srow + i * 32) * Kpad + k0 + scol;
      __builtin_amdgcn_global_load_lds((const __attribute__((address_space(1))) void*)g,
        (__attribute__((address_space(3))) void*)(Bs + (srow + i * 32) * 64 + scol), 16, 0, 0);
    }
    __syncthreads();
    // ---- MFMA: 2 k-halves of 32 ----
    #pragma unroll
    for(int s = 0; s < 2; s++){
      s16x8 af[4], bfr[4];
      #pragma unroll
      for(int i = 0; i < 4; i++)
        af[i]  = *(const s16x8*)(As + (wm + i * 16 + frow) * 64 + s * 32 + fq * 8);
      #pragma unroll
      for(int j = 0; j < 4; j++)
        bfr[j] = *(const s16x8*)(Bs + (wn + j * 16 + frow) * 64 + s * 32 + fq * 8);
      #pragma unroll
      for(int i = 0; i < 4; i++)
        #pragma unroll
        for(int j = 0; j < 4; j++)
          acc[i][j] = __builtin_amdgcn_mfma_f32_16x16x32_bf16(af[i], bfr[j], acc[i][j], 0, 0, 0);
    }
  }

  const int crow = fq << 2;   // C/D: col=lane&15, row=(lane>>4)*4+reg [m89]
  const int ccol = frow;
  auto bload = [&](int idx) -> float {
    return flag ? ((const float*)bias)[idx] : bf2f(((const u16*)bias)[idx]);
  };

  if(EPI < 2){
    #pragma unroll
    for(int j = 0; j < 4; j++){
      int n = n0 + wn + j * 16 + ccol;
      float bv = bload(task * biasStride + n);
      #pragma unroll
      for(int i = 0; i < 4; i++)
        #pragma unroll
        for(int r = 0; r < 4; r++){
          int m = m0l + wm + i * 16 + crow + r;
          float v = acc[i][j][r] + bv;
          if(EPI == 0 && v < 0.f) v = 0.f;
          C[(size_t)m * ldc + n] = f2bf(v);
        }
    }
  } else {
    int rp[4][4];
    #pragma unroll
    for(int i = 0; i < 4; i++)
      #pragma unroll
      for(int r = 0; r < 4; r++)
        rp[i][r] = perm[m0g + wm + i * 16 + crow + r];
    #pragma unroll
    for(int j = 0; j < 4; j++){
      int n = n0 + wn + j * 16 + ccol;
      if(n < Nact){
        float bv = bload(task * biasStride + n);
        #pragma unroll
        for(int i = 0; i < 4; i++)
          #pragma unroll
          for(int r = 0; r < 4; r++){
            int rr = rp[i][r];
            if(rr >= 0){
              float v = acc[i][j][r] + bv;
              stout(outp, (size_t)rr * INF + n, 1.f / (1.f + __expf(-v)), flag);
            }
          }
      }
    }
  }
}

extern "C" void kernel_launch(void* const* d_in, const int* in_sizes, int n_in,
                              void* d_out, int out_size, void* d_ws, size_t ws_size,
                              hipStream_t stream) {
  const void* x    = d_in[0];
  const int*  task = (const int*)d_in[1];
  const void* eps  = d_in[2];
  const void* W1  = d_in[3];  const void* b1  = d_in[4];
  const void* W2  = d_in[5];  const void* b2  = d_in[6];
  const void* W3  = d_in[7];  const void* b3  = d_in[8];
  const void* W4  = d_in[9];  const void* b4  = d_in[10];
  const void* Ws1 = d_in[11]; const void* bs1 = d_in[12];
  const void* Ws2 = d_in[13]; const void* bs2 = d_in[14];
  const void* Wh1 = d_in[15]; const void* bh1 = d_in[16];
  const void* Wh2 = d_in[17]; const void* bh2 = d_in[18];
  void* out = d_out;
  char* ws  = (char*)d_ws;

  int* meta = (int*)ws;
  const char* zp = ws + O_ZP;
  int* perm = (int*)(ws + O_PERM);
  u16* Wt   = (u16*)(ws + O_WT);

  size_t avail = ws_size > O_BUF ? ws_size - O_BUF : 0;
  int CH = (int)(avail / T_ALL);
  if(CH < 1) CH = 1;
  if(CH > MTILES) CH = MTILES;

  u16* Ha   = (u16*)(ws + O_BUF);
  u16* Hb   = Ha + (size_t)CH * 128 * HD;
  u16* ENCb = Hb + (size_t)CH * 128 * HD;
  u16* Z    = ENCb + (size_t)CH * 128 * 256;

  (void)hipMemsetAsync(ws, 0, 4096, stream);                  // meta + zero page
  (void)hipMemsetAsync(perm, 0xFF, (size_t)MCAP * 4, stream); // pad rows = -1
  k_detect <<<1, 256, 0, stream>>>((const u16*)eps, meta);
  k_count  <<<32, 256, 0, stream>>>(task, meta);
  k_plan   <<<1, 64, 0, stream>>>(meta);
  k_scatter<<<32, 256, 0, stream>>>(task, meta, perm);

  for(int t0 = 0; t0 < MTILES; t0 += CH){
    int ct = (MTILES - t0 < CH) ? (MTILES - t0) : CH;
    // enc1: gather x (K=784 pad 832) * W1t -> Ha, relu
    k_wt<<<dim3(26, 32, TT), 256, 0, stream>>>(W1, INF, HD, Wt, 832, HD, meta);
    k_gemm<1,0><<<ct*8, 256, 0, stream>>>(x, INF, Wt, (long long)HD*832,
                                          b1, HD, Ha, HD, 832, INF, HD, t0, 8, meta, perm, zp, out);
    // enc2
    k_wt<<<dim3(32, 32, TT), 256, 0, stream>>>(W2, HD, HD, Wt, HD, HD, meta);
    k_gemm<0,0><<<ct*8, 256, 0, stream>>>(Ha, HD, Wt, (long long)HD*HD,
                                          b2, HD, Hb, HD, HD, HD, HD, t0, 8, meta, perm, zp, out);
    // enc3
    k_wt<<<dim3(32, 32, TT), 256, 0, stream>>>(W3, HD, HD, Wt, HD, HD, meta);
    k_gemm<0,0><<<ct*8, 256, 0, stream>>>(Hb, HD, Wt, (long long)HD*HD,
                                          b3, HD, Ha, HD, HD, HD, HD, t0, 8, meta, perm, zp, out);
    // enc4 -> ENCb (bf16, 256 wide)
    k_wt<<<dim3(32, 8, TT), 256, 0, stream>>>(W4, HD, 256, Wt, HD, 256, meta);
    k_gemm<0,1><<<ct*2, 256, 0, stream>>>(Ha, HD, Wt, (long long)256*HD,
                                          b4, 256, ENCb, 256, HD, HD, 256, t0, 2, meta, perm, zp, out);
    // mu / log_sigma to d_out + z
    k_z<<<ct*64, 256, 0, stream>>>(ENCb, eps, perm, Z, out, t0, meta);
    // dec s1 (shared): Z(K=128) * Ws1t -> Ha, relu
    k_wt<<<dim3(4, 32, 1), 256, 0, stream>>>(Ws1, LD, HD, Wt, LD, HD, meta);
    k_gemm<0,0><<<ct*8, 256, 0, stream>>>(Z, LD, Wt, 0LL,
                                          bs1, 0, Ha, HD, LD, LD, HD, t0, 8, meta, perm, zp, out);
    // dec s2 (shared)
    k_wt<<<dim3(32, 32, 1), 256, 0, stream>>>(Ws2, HD, HD, Wt, HD, HD, meta);
    k_gemm<0,0><<<ct*8, 256, 0, stream>>>(Ha, HD, Wt, 0LL,
                                          bs2, 0, Hb, HD, HD, HD, HD, t0, 8, meta, perm, zp, out);
    // dec h1 (per-task)
    k_wt<<<dim3(32, 32, TT), 256, 0, stream>>>(Wh1, HD, HD, Wt, HD, HD, meta);
    k_gemm<0,0><<<ct*8, 256, 0, stream>>>(Hb, HD, Wt, (long long)HD*HD,
                                          bh1, HD, Ha, HD, HD, HD, HD, t0, 8, meta, perm, zp, out);
    // dec h2 (per-task): sigmoid + scatter to d_out (N=784 pad 896)
    k_wt<<<dim3(32, 28, TT), 256, 0, stream>>>(Wh2, HD, INF, Wt, HD, 896, meta);
    k_gemm<0,2><<<ct*7, 256, 0, stream>>>(Ha, HD, Wt, (long long)896*HD,
                                          bh2, INF, (u16*)out, INF, HD, HD, INF, t0, 7, meta, perm, zp, out);
  }
}